// Round 7
// baseline (448.372 us; speedup 1.0000x reference)
//
#include <hip/hip_runtime.h>
#include <hip/hip_bf16.h>

// Problem constants (fixed by the reference)
constexpr int M_ = 8192;      // batch
constexpr int N_ = 4096;      // out_dim
constexpr int K_ = 4096;      // in_dim
constexpr int CBOOK = 65536;
constexpr int HA = 10007, HB = 20011;
constexpr int HC3 = 3 * 40009;     // 120027
// sign hash: all constants odd => sign = +1 iff (o+i) even

// Algebra (CBOOK = 2^16, HB odd => invertible mod 2^16):
//   197*HB ≡ HA (mod 2^16)  =>  idx(n,k) = (U*HB + HC3) & 0xFFFF,
//   U = (197n + k) & 0xFFFF; parity(U) = parity(n+k) => sign folds into U.
//   W[n][k] = P2ext[(197n+k) & 0xFFFF],
//   P2ext[u] = (u&1 ? -1 : +1) * cb[(u*HB + HC3) & 0xFFFF]   (65536-periodic)
// Used ONLY in prep (one aligned 16B load per output slot instead of 8
// scattered cb gathers); the GEMM reads a linear pre-swizzled W image.
constexpr int C0 = 197;

constexpr int BM = 256, BN = 256, BK = 32;
constexpr int NKT = K_ / BK;               // 128 K-tiles

using bf16x8 = __bf16 __attribute__((ext_vector_type(8)));
using f32x4  = float __attribute__((ext_vector_type(4)));
using u16x8  = unsigned short __attribute__((ext_vector_type(8)));

typedef __attribute__((address_space(3))) void lds_void_t;
typedef const __attribute__((address_space(1))) void gbl_void_t;

static __device__ __forceinline__ unsigned short f2bf(float f) {
    __bf16 h = (__bf16)f;   // RNE on gfx950
    return __builtin_bit_cast(unsigned short, h);
}

// ---------------------------------------------------------------------------
// prep stage 1: P2 phase-copy table  P2p[p][i] = P2ext[i+p], p<8, i<65536.
// 1 MiB; gives every (lane,slot) a 16B-aligned contiguous window of P2ext.
// ---------------------------------------------------------------------------
constexpr int P2N   = 8 * 65536;           // 524288 elems, 1 MiB
constexpr int P2B   = P2N / 256;           // 2048 blocks

__global__ __launch_bounds__(256) void prep_p2(const float* __restrict__ cb,
                                               unsigned short* __restrict__ P2p) {
    const int t = blockIdx.x * 256 + threadIdx.x;   // [0, 2^19)
    const int p = t >> 16;
    const int i = t & 65535;
    const int u = i + p;                            // u*HB < 2^31
    float v = cb[(u * HB + HC3) & (CBOOK - 1)];
    if (u & 1) v = -v;
    P2p[t] = f2bf(v);
}

// ---------------------------------------------------------------------------
// prep stage 2 (merged):
//   blocks [0, GENB): W in LDS-image order (swizzle baked in), via P2p:
//     slot t: row = (t&1023)>>2, blk = t&3, kt = (t>>10)&127, nb = t>>17
//     key = (row>>1)&3; n = nb*256+row; k0 = kt*32 + ((blk^key)<<3)
//     u0 = (197n + k0) & 0xFFFF;  out[j] = P2ext[u0+j] = P2p[u0&7][u0&~7 + j]
//   blocks [GENB, GENB+CONVB): x fp32 -> bf16 row-major (A staging source)
// ---------------------------------------------------------------------------
constexpr int GENB  = N_ * K_ / 8 / 256;   // 8192
constexpr int CONVB = M_ * K_ / 8 / 256;   // 16384

__global__ __launch_bounds__(256) void prep_main(const float* __restrict__ x,
                                                 const unsigned short* __restrict__ P2p,
                                                 unsigned short* __restrict__ Wf,
                                                 unsigned short* __restrict__ xb) {
    const int b = blockIdx.x;
    if (b < GENB) {
        const int t    = b * 256 + threadIdx.x;   // [0, 2^21) 16B slots
        const int slot = t & 1023;
        const int kt   = (t >> 10) & 127;
        const int nb   = t >> 17;
        const int row  = slot >> 2;
        const int key  = (row >> 1) & 3;
        const int n  = (nb << 8) + row;
        const int k0 = (kt << 5) + (((slot & 3) ^ key) << 3);
        const int u0 = (C0 * n + k0) & (CBOOK - 1);
        const u16x8 w = *reinterpret_cast<const u16x8*>(
            P2p + ((u0 & 7) << 16) + (u0 & 65528));     // one aligned 16B load
        *reinterpret_cast<u16x8*>(&Wf[(size_t)t * 8]) = w;   // coalesced
    } else {
        const size_t t = (size_t)(b - GENB) * 256 + threadIdx.x;
        const float4* p = reinterpret_cast<const float4*>(x) + t * 2;
        const float4 a = p[0], c = p[1];
        u16x8 out;
        out[0] = f2bf(a.x); out[1] = f2bf(a.y); out[2] = f2bf(a.z); out[3] = f2bf(a.w);
        out[4] = f2bf(c.x); out[5] = f2bf(c.y); out[6] = f2bf(c.z); out[7] = f2bf(c.w);
        reinterpret_cast<u16x8*>(xb)[t] = out;
    }
}

// ---------------------------------------------------------------------------
// GEMM: C[M][N] = A[M][K] * W[N][K]^T + bias
// 256x256 tile, BK=32, 512 threads (8 waves 2Mx4N, wave tile 128x64).
// 4-deep LDS ring (128 KB).  Schedule per window kt (ONE barrier/window):
//   vmcnt(4) cert [stage(kt+1) landed] -> s_barrier -> STAGE(kt+3)
//   -> MFMA cluster with afr[mt] reloads for kt+1 interleaved, ENFORCED by
//      sched_group_barrier {4 MFMA, 1 DS_READ} x 8 (T19).  Without the SGB,
//      LLVM re-clusters the dep-free reloads into a serial block and the
//      LDS wall (96 b128 reads ~= 1152 cyc/CU/window) serializes against
//      the MFMA wall (1242 cyc) -- R6 counters: both pipes ~55% busy,
//      anti-correlated.  The 4 bfr tail reads CANNOT be stolen into the
//      interleave slots: they have a WAR dep on bfr[nt] used by mt=7.
//   -> 4-read bfr tail (bfr live through the cluster; no reg headroom at
//      ~124 VGPR + 128 AGPR to double-buffer it)
// Loop unrolled x4 so ring-slot offsets are compile-time immediates.
// Cross-wave LDS WAR is safe: a wave's reads of slot (kt+1)&3 retire before
// its MFMAs(kt+1) (lgkm), hence before it reaches barrier(kt+2), hence
// before any wave issues STAGE(kt+5) which is the next writer of that slot.
// ---------------------------------------------------------------------------
__global__ __launch_bounds__(512, 2) void gemm_kernel(
        const unsigned short* __restrict__ A,    // xb row-major [M][K]
        const unsigned short* __restrict__ Wf,   // LDS-image W
        const float* __restrict__ bias,
        float* __restrict__ C) {
    __shared__ __align__(16) unsigned short sm[4 * 8192 * 2];  // 128 KB
    unsigned short* As = sm;                 // [4][8192]
    unsigned short* Bs = sm + 4 * 8192;      // [4][8192]

    const int tid  = threadIdx.x;
    const int lane = tid & 63;
    const int w    = tid >> 6;          // wave 0..7
    const int wm   = w >> 2;            // 0..1 -> rows wm*128
    const int wn   = w & 3;             // 0..3 -> cols wn*64
    const int m0 = blockIdx.y * BM;
    const int n0 = blockIdx.x * BN;

    const int quad = lane >> 4;         // 0..3
    const int l16  = lane & 15;

    // --- staging addressing (slot s = r*512 + tid: row=s>>2, blk=s&3,
    //     swizzle key=(row>>1)&3 baked into both source layouts) ---
    const int sblk = (lane & 3) ^ ((lane >> 3) & 3);
    const unsigned short* aLane =
        A + (size_t)(m0 + w * 16 + (lane >> 2)) * K_ + sblk * 8;
    const unsigned short* bLane =
        Wf + (size_t)blockIdx.x * NKT * 8192 + tid * 8;   // fully linear

    // --- ds-read addressing (swizzled, 2-way max -> conflict-free) ---
    const int rblk = (quad ^ ((l16 >> 1) & 3)) * 8;
    const unsigned short* aRd = As + (wm * 128 + l16) * 32 + rblk;
    const unsigned short* bRd = Bs + (wn * 64 + l16) * 32 + rblk;

    f32x4 acc[8][4] = {};               // wave tile 128x64 (AGPRs)
    bf16x8 bfr[4], afr[8];              // current window's fragments

    // stage K-tile kt into ring slot bs (4 vmem loads per wave)
    auto STAGE = [&](int kt, int bs) {
#pragma unroll
        for (int r = 0; r < 2; ++r) {
            __builtin_amdgcn_global_load_lds(
                (gbl_void_t*)(aLane + (size_t)r * 128 * K_ + (size_t)kt * BK),
                (lds_void_t*)(As + bs * 8192 + (r * 512 + w * 64) * 8), 16, 0, 0);
            __builtin_amdgcn_global_load_lds(
                (gbl_void_t*)(bLane + (size_t)kt * 8192 + r * 4096),
                (lds_void_t*)(Bs + bs * 8192 + (r * 512 + w * 64) * 8), 16, 0, 0);
        }
    };

    STAGE(0, 0); STAGE(1, 1); STAGE(2, 2);
    asm volatile("s_waitcnt vmcnt(8)" ::: "memory");   // stage(0) landed
    __builtin_amdgcn_s_barrier();
    // preload fragments of K-tile 0 (slot 0)
#pragma unroll
    for (int nt = 0; nt < 4; ++nt)
        bfr[nt] = *reinterpret_cast<const bf16x8*>(bRd + nt * 512);
#pragma unroll
    for (int mt = 0; mt < 8; ++mt)
        afr[mt] = *reinterpret_cast<const bf16x8*>(aRd + mt * 512);

    for (int kt0 = 0; kt0 < NKT; kt0 += 4) {
#pragma unroll
        for (int s = 0; s < 4; ++s) {
            const int kt = kt0 + s;
            // certify stage(kt+1) landed; keep stage(kt+2) (4 loads) in flight
            if (kt + 2 < NKT)      asm volatile("s_waitcnt vmcnt(4)" ::: "memory");
            else if (kt + 1 < NKT) asm volatile("s_waitcnt vmcnt(0)" ::: "memory");
            __builtin_amdgcn_s_barrier();            // open window kt

            if (kt + 3 < NKT) STAGE(kt + 3, (s + 3) & 3);

            const int rs = ((s + 1) & 3) * 8192;     // reload slot (imm offs)
            __builtin_amdgcn_s_setprio(1);
#pragma unroll
            for (int mt = 0; mt < 8; ++mt) {
#pragma unroll
                for (int nt = 0; nt < 4; ++nt)
                    acc[mt][nt] = __builtin_amdgcn_mfma_f32_16x16x32_bf16(
                        afr[mt], bfr[nt], acc[mt][nt], 0, 0, 0);
                // afr[mt] dead now: reload for window kt+1 (slot certified at
                // this window's open; at kt=NKT-1 reads stale data, never used)
                afr[mt] = *reinterpret_cast<const bf16x8*>(aRd + rs + mt * 512);
                // T19: enforce {4 MFMA, 1 ds_read} interleave in the emitted
                // schedule (LLVM otherwise re-clusters the dep-free reloads).
                __builtin_amdgcn_sched_group_barrier(0x008, 4, 0);  // 4 MFMA
                __builtin_amdgcn_sched_group_barrier(0x100, 1, 0);  // 1 DS read
            }
            __builtin_amdgcn_s_setprio(0);
            // bfr tail reload (4 reads; latency covered by next barrier+stage)
#pragma unroll
            for (int nt = 0; nt < 4; ++nt)
                bfr[nt] = *reinterpret_cast<const bf16x8*>(bRd + rs + nt * 512);
            __builtin_amdgcn_sched_group_barrier(0x100, 4, 0);      // bfr tail
        }
    }

    // epilogue: C/D layout col=lane&15, row=quad*4+r (m89/m91-verified)
#pragma unroll
    for (int nt = 0; nt < 4; ++nt) {
        const int col = n0 + wn * 64 + nt * 16 + l16;
        const float bv = bias[col];
#pragma unroll
        for (int mt = 0; mt < 8; ++mt) {
            const int rowb = m0 + wm * 128 + mt * 16 + quad * 4;
#pragma unroll
            for (int r = 0; r < 4; ++r)
                C[(size_t)(rowb + r) * N_ + col] = acc[mt][nt][r] + bv;
        }
    }
}

// ---------------------------------------------------------------------------
// Correctness-insurance fallback (only if ws too small; slow but exact)
// ---------------------------------------------------------------------------
__global__ __launch_bounds__(256) void naive_kernel(const float* __restrict__ x,
                                                    const float* __restrict__ cb,
                                                    const float* __restrict__ bias,
                                                    float* __restrict__ out) {
    const size_t t = (size_t)blockIdx.x * 256 + threadIdx.x;
    const int row = (int)(t / N_);
    const int col = (int)(t % N_);
    float s = bias[col];
    const float* xr = x + (size_t)row * K_;
    const int h = col * HA + HC3;
    for (int i = 0; i < K_; ++i) {
        float v = cb[(h + i * HB) & (CBOOK - 1)];
        s += xr[i] * (((col ^ i) & 1) ? -v : v);
    }
    out[t] = s;
}

extern "C" void kernel_launch(void* const* d_in, const int* in_sizes, int n_in,
                              void* d_out, int out_size, void* d_ws, size_t ws_size,
                              hipStream_t stream) {
    const float* x    = (const float*)d_in[0];
    const float* cb   = (const float*)d_in[1];
    const float* bias = (const float*)d_in[2];
    float* out = (float*)d_out;

    const size_t wBytes = (size_t)N_ * K_ * sizeof(unsigned short);  // 32 MiB
    const size_t xBytes = (size_t)M_ * K_ * sizeof(unsigned short);  // 64 MiB
    const size_t pBytes = (size_t)P2N * sizeof(unsigned short);      // 1 MiB

    if (ws_size >= wBytes + xBytes + pBytes) {
        unsigned short* Wf  = (unsigned short*)d_ws;
        unsigned short* xb  = (unsigned short*)((char*)d_ws + wBytes);
        unsigned short* P2p = (unsigned short*)((char*)d_ws + wBytes + xBytes);
        prep_p2<<<P2B, 256, 0, stream>>>(cb, P2p);
        prep_main<<<GENB + CONVB, 256, 0, stream>>>(x, P2p, Wf, xb);
        // grid x = 16 n-strips: XCD = linear%8 = x%8; each XCD's Wf slice is
        // 2 strips x 2MB = 4MB = its L2.  B stream stays L2-resident.
        gemm_kernel<<<dim3(N_ / BN, M_ / BM), 512, 0, stream>>>(xb, Wf, bias, out);
    } else {
        naive_kernel<<<(int)((size_t)M_ * N_ / 256), 256, 0, stream>>>(x, cb, bias, out);
    }
}